// Round 2
// baseline (1004.335 us; speedup 1.0000x reference)
//
#include <hip/hip_runtime.h>
#include <stdint.h>

typedef short    v8s  __attribute__((ext_vector_type(8)));
typedef float    v4f  __attribute__((ext_vector_type(4)));
typedef unsigned short u16x8 __attribute__((ext_vector_type(8)));
typedef unsigned short ushort_t;

#define NB   32
#define NN   1024
#define CD   896
#define GD   384
#define HD   256
#define OD   1280

static __device__ __forceinline__ unsigned short f2bf(float f) {
    union { float f; unsigned u; } v; v.f = f;
    unsigned r = v.u + 0x7fffu + ((v.u >> 16) & 1u);
    return (unsigned short)(r >> 16);
}

static __device__ __forceinline__ v4f mfma16(v8s a, v8s b, v4f c) {
    return __builtin_amdgcn_mfma_f32_16x16x32_bf16(a, b, c, 0, 0, 0);
}

// stage 16 fp32 -> 16 bf16 into LDS (two 16B stores)
static __device__ __forceinline__ void stage_cvt16(const float* __restrict__ src, ushort_t* dst) {
    const float4* s4 = (const float4*)src;
    float4 f0 = s4[0], f1 = s4[1], f2 = s4[2], f3 = s4[3];
    u16x8 p0, p1;
    p0[0]=f2bf(f0.x); p0[1]=f2bf(f0.y); p0[2]=f2bf(f0.z); p0[3]=f2bf(f0.w);
    p0[4]=f2bf(f1.x); p0[5]=f2bf(f1.y); p0[6]=f2bf(f1.z); p0[7]=f2bf(f1.w);
    p1[0]=f2bf(f2.x); p1[1]=f2bf(f2.y); p1[2]=f2bf(f2.z); p1[3]=f2bf(f2.w);
    p1[4]=f2bf(f3.x); p1[5]=f2bf(f3.y); p1[6]=f2bf(f3.z); p1[7]=f2bf(f3.w);
    *(u16x8*)dst = p0;
    *(u16x8*)(dst + 8) = p1;
}

static __device__ __forceinline__ void stage_copy16(const ushort_t* __restrict__ src, ushort_t* dst) {
    const u16x8* s = (const u16x8*)src;
    u16x8 a = s[0], b = s[1];
    *(u16x8*)dst = a;
    *(u16x8*)(dst + 8) = b;
}

// ---------------- weight transpose+convert: W[k][n] f32 -> Wt[n][k] bf16 ----
__global__ void convw_kernel(const float* __restrict__ W, ushort_t* __restrict__ Wt, int Kd) {
    int idx = blockIdx.x * 256 + threadIdx.x;      // total = Kd*256
    int k = idx >> 8, n = idx & 255;
    Wt[(size_t)n * Kd + k] = f2bf(W[idx]);
}

__global__ void zero_kernel(float* __restrict__ p, int n) {
    int i = blockIdx.x * 256 + threadIdx.x;
    if (i < n) p[i] = 0.f;
}

// ---------------- cluster pooled mean: 512 blocks, float4, 4-acc ILP --------
__global__ void pool_kernel(const float* __restrict__ cf, float* __restrict__ pooled) {
    int b = blockIdx.y, chunk = blockIdx.x, t = threadIdx.x;
    if (t >= 224) return;                          // 224 float4 = 896 floats
    const float4* p = (const float4*)(cf + (size_t)(b * NN + chunk * 64) * CD) + t;
    float4 s0{0,0,0,0}, s1{0,0,0,0}, s2{0,0,0,0}, s3{0,0,0,0};
    #pragma unroll 1
    for (int n = 0; n < 64; n += 4) {
        float4 v0 = p[(size_t)(n + 0) * 224];
        float4 v1 = p[(size_t)(n + 1) * 224];
        float4 v2 = p[(size_t)(n + 2) * 224];
        float4 v3 = p[(size_t)(n + 3) * 224];
        s0.x += v0.x; s0.y += v0.y; s0.z += v0.z; s0.w += v0.w;
        s1.x += v1.x; s1.y += v1.y; s1.z += v1.z; s1.w += v1.w;
        s2.x += v2.x; s2.y += v2.y; s2.z += v2.z; s2.w += v2.w;
        s3.x += v3.x; s3.y += v3.y; s3.z += v3.z; s3.w += v3.w;
    }
    const float sc = 1.f / 1024.f;
    float* dst = pooled + b * CD + t * 4;
    atomicAdd(dst + 0, (s0.x + s1.x + s2.x + s3.x) * sc);
    atomicAdd(dst + 1, (s0.y + s1.y + s2.y + s3.y) * sc);
    atomicAdd(dst + 2, (s0.z + s1.z + s2.z + s3.z) * sc);
    atomicAdd(dst + 3, (s0.w + s1.w + s2.w + s3.w) * sc);
}

// ---------------- projection GEMM: C_bf16[M,256] = A_f32[M,KD] @ Wt^T + bias -
template<int KD>
__global__ __launch_bounds__(256) void proj_kernel(
    const float* __restrict__ A, const ushort_t* __restrict__ Wt,
    const float* __restrict__ bias, ushort_t* __restrict__ C)
{
    __shared__ ushort_t lA[128 * 40];
    __shared__ ushort_t lB[128 * 40];
    const int tid  = threadIdx.x;
    const int m0   = blockIdx.x * 128;
    const int n0   = blockIdx.y * 128;
    const int lane = tid & 63, wave = tid >> 6;
    const int l15  = lane & 15, quad = lane >> 4;
    const int wrow = (wave >> 1) * 64, wcol = (wave & 1) * 64;
    const int srow = tid >> 1, shalf = tid & 1;

    v4f acc[4][4];
    #pragma unroll
    for (int i = 0; i < 4; ++i)
        #pragma unroll
        for (int j = 0; j < 4; ++j) acc[i][j] = v4f{0.f, 0.f, 0.f, 0.f};

    for (int kt = 0; kt < KD / 32; ++kt) {
        stage_cvt16(A + (size_t)(m0 + srow) * KD + kt * 32 + shalf * 16,
                    &lA[srow * 40 + shalf * 16]);
        stage_copy16(Wt + (size_t)(n0 + srow) * KD + kt * 32 + shalf * 16,
                     &lB[srow * 40 + shalf * 16]);
        __syncthreads();
        v8s af[4], bfr[4];
        #pragma unroll
        for (int rt = 0; rt < 4; ++rt) af[rt]  = *(const v8s*)&lA[(wrow + rt * 16 + l15) * 40 + quad * 8];
        #pragma unroll
        for (int ct = 0; ct < 4; ++ct) bfr[ct] = *(const v8s*)&lB[(wcol + ct * 16 + l15) * 40 + quad * 8];
        #pragma unroll
        for (int rt = 0; rt < 4; ++rt)
            #pragma unroll
            for (int ct = 0; ct < 4; ++ct)
                acc[rt][ct] = mfma16(af[rt], bfr[ct], acc[rt][ct]);
        __syncthreads();
    }

    #pragma unroll
    for (int ct = 0; ct < 4; ++ct) {
        int col = n0 + wcol + ct * 16 + l15;
        float bv = bias[col];
        #pragma unroll
        for (int rt = 0; rt < 4; ++rt)
            #pragma unroll
            for (int r = 0; r < 4; ++r) {
                int row = m0 + wrow + rt * 16 + quad * 4 + r;
                C[(size_t)row * 256 + col] = f2bf(acc[rt][ct][r] + bv);
            }
    }
}

// ---------------- fused attention: QK^T + log(w) -> softmax -> attn + colsum
// Register-resident S: 256 threads (4 waves), block owns 16 rows x 1024 cols.
// Each wave: 256 cols, acc[16] v4f (64 VGPR). LDS only for 512B row reduce.
// acc is SEEDED with 16*log(cw+1e-8) so cw-load latency hides under QK MFMAs:
//   final = 0.0625*(seed + QK) = log(cw) + 0.0625*QK.
__global__ __launch_bounds__(256, 4) void attn_kernel(
    const ushort_t* __restrict__ Qb, const ushort_t* __restrict__ Kb,
    const float* __restrict__ cw,
    float* __restrict__ attn, float* __restrict__ colsum)
{
    __shared__ float red[2][4][16];
    const int bat = blockIdx.x;          // batch on x -> batch%8 pins to XCD (K L2 reuse)
    const int m0  = blockIdx.y * 16;
    const int tid = threadIdx.x;
    const int lane = tid & 63, wave = tid >> 6;
    const int l15 = lane & 15, quad = lane >> 4;
    const int n0w = wave * 256;

    // ---- seed acc with 16*log(cw) (issues all 64 loads up front)
    v4f acc[16];
    const float* cwp = cw + ((size_t)bat << 20);
    #pragma unroll
    for (int ct = 0; ct < 16; ++ct) {
        const int col = n0w + ct * 16 + l15;
        #pragma unroll
        for (int r = 0; r < 4; ++r) {
            float w = cwp[(size_t)(m0 + quad * 4 + r) * NN + col];
            acc[ct][r] = 16.f * __logf(w + 1e-8f);
        }
    }

    // ---- QK^T: ks-outer so only 1 Q-frag live; K frags transient
    const ushort_t* qrow = Qb + (size_t)(bat * NN + m0 + l15) * HD + quad * 8;
    const ushort_t* krow = Kb + (size_t)(bat * NN + n0w + l15) * HD + quad * 8;
    #pragma unroll 1
    for (int ks = 0; ks < 8; ++ks) {
        v8s af = *(const v8s*)(qrow + ks * 32);
        #pragma unroll
        for (int ct = 0; ct < 16; ++ct) {
            v8s bf = *(const v8s*)(krow + (size_t)(ct * 16) * HD + ks * 32);
            acc[ct] = mfma16(af, bf, acc[ct]);
        }
    }

    // ---- scale
    #pragma unroll
    for (int ct = 0; ct < 16; ++ct)
        #pragma unroll
        for (int r = 0; r < 4; ++r) acc[ct][r] *= 0.0625f;

    // ---- row max: in-lane over ct, shfl over l15, LDS over 4 waves
    float mr[4];
    #pragma unroll
    for (int r = 0; r < 4; ++r) {
        float m = acc[0][r];
        #pragma unroll
        for (int ct = 1; ct < 16; ++ct) m = fmaxf(m, acc[ct][r]);
        #pragma unroll
        for (int off = 1; off <= 8; off <<= 1) m = fmaxf(m, __shfl_xor(m, off));
        mr[r] = m;
    }
    if (l15 == 0) {
        #pragma unroll
        for (int r = 0; r < 4; ++r) red[0][wave][quad * 4 + r] = mr[r];
    }
    __syncthreads();
    #pragma unroll
    for (int r = 0; r < 4; ++r) {
        const int row = quad * 4 + r;
        mr[r] = fmaxf(fmaxf(red[0][0][row], red[0][1][row]),
                      fmaxf(red[0][2][row], red[0][3][row]));
    }

    // ---- exp + row sum
    float sr[4];
    #pragma unroll
    for (int r = 0; r < 4; ++r) {
        float s = 0.f;
        #pragma unroll
        for (int ct = 0; ct < 16; ++ct) {
            float p = __expf(acc[ct][r] - mr[r]);
            acc[ct][r] = p;
            s += p;
        }
        #pragma unroll
        for (int off = 1; off <= 8; off <<= 1) s += __shfl_xor(s, off);
        sr[r] = s;
    }
    if (l15 == 0) {
        #pragma unroll
        for (int r = 0; r < 4; ++r) red[1][wave][quad * 4 + r] = sr[r];
    }
    __syncthreads();
    #pragma unroll
    for (int r = 0; r < 4; ++r) {
        const int row = quad * 4 + r;
        sr[r] = 1.0f / (red[1][0][row] + red[1][1][row] + red[1][2][row] + red[1][3][row]);
    }

    // ---- normalize, write attn, accumulate colsum
    float* abase = attn + ((size_t)bat << 20) + (size_t)m0 * NN;
    #pragma unroll
    for (int ct = 0; ct < 16; ++ct) {
        const int col = n0w + ct * 16 + l15;
        float c = 0.f;
        #pragma unroll
        for (int r = 0; r < 4; ++r) {
            float p = acc[ct][r] * sr[r];
            abase[(size_t)(quad * 4 + r) * NN + col] = p;
            c += p;
        }
        c += __shfl_xor(c, 16);
        c += __shfl_xor(c, 32);
        if (quad == 0) atomicAdd(&colsum[(size_t)bat * NN + col], c);
    }
}

// ---------------- weighted gf pooling: gws[b,:] = (1/N) colsum[b,:] @ gf[b] -
// grid (8 chunks, 32 b), 192 threads (float2 over GD=384), 4-acc ILP
__global__ __launch_bounds__(192) void wpool_kernel(
    const float* __restrict__ gf, const float* __restrict__ colsum,
    float* __restrict__ gws)
{
    const int b = blockIdx.y, m0 = blockIdx.x * 128, t = threadIdx.x;
    const float2* base = (const float2*)(gf + (size_t)(b * NN + m0) * GD);
    const float* wbase = colsum + (size_t)b * NN + m0;
    const float sc = 1.f / 1024.f;
    float sx0 = 0.f, sy0 = 0.f, sx1 = 0.f, sy1 = 0.f;
    float sx2 = 0.f, sy2 = 0.f, sx3 = 0.f, sy3 = 0.f;
    #pragma unroll 1
    for (int m = 0; m < 128; m += 4) {
        float w0 = wbase[m + 0] * sc; float2 v0 = base[(size_t)(m + 0) * (GD / 2) + t];
        float w1 = wbase[m + 1] * sc; float2 v1 = base[(size_t)(m + 1) * (GD / 2) + t];
        float w2 = wbase[m + 2] * sc; float2 v2 = base[(size_t)(m + 2) * (GD / 2) + t];
        float w3 = wbase[m + 3] * sc; float2 v3 = base[(size_t)(m + 3) * (GD / 2) + t];
        sx0 += w0 * v0.x; sy0 += w0 * v0.y;
        sx1 += w1 * v1.x; sy1 += w1 * v1.y;
        sx2 += w2 * v2.x; sy2 += w2 * v2.y;
        sx3 += w3 * v3.x; sy3 += w3 * v3.y;
    }
    atomicAdd(&gws[b * GD + 2 * t + 0], (sx0 + sx1) + (sx2 + sx3));
    atomicAdd(&gws[b * GD + 2 * t + 1], (sy0 + sy1) + (sy2 + sy3));
}

// ---------------- tiny V projection: gpool[b,d] = gws[b,:] @ Wv[:,d] + bv[d] -
__global__ __launch_bounds__(256) void vproj_kernel(
    const float* __restrict__ gws, const float* __restrict__ Wv,
    const float* __restrict__ bv, float* __restrict__ gpool)
{
    const int b = blockIdx.x, d = threadIdx.x;
    const float* g = gws + (size_t)b * GD;
    float a0 = 0.f, a1 = 0.f, a2 = 0.f, a3 = 0.f;
    #pragma unroll 2
    for (int k = 0; k < GD; k += 4) {
        a0 += g[k + 0] * Wv[(size_t)(k + 0) * HD + d];
        a1 += g[k + 1] * Wv[(size_t)(k + 1) * HD + d];
        a2 += g[k + 2] * Wv[(size_t)(k + 2) * HD + d];
        a3 += g[k + 3] * Wv[(size_t)(k + 3) * HD + d];
    }
    gpool[b * HD + d] = bv[d] + (a0 + a1) + (a2 + a3);
}

// ---------------- tails (fp32 vector, 4-acc ILP) -----------------------------
__global__ void tail1_kernel(const float* __restrict__ pooled, const float* __restrict__ gpool,
                             const float* __restrict__ Wcp, const float* __restrict__ bcp,
                             const float* __restrict__ Wgp, const float* __restrict__ bgp,
                             float* __restrict__ combined)
{
    int idx = blockIdx.x * 256 + threadIdx.x;  // 32*1280
    int b = idx / OD, c = idx % OD;
    float a0 = 0.f, a1 = 0.f, a2 = 0.f, a3 = 0.f, bias;
    if (c < 640) {
        bias = bcp[c];
        const float* a = pooled + b * CD;
        #pragma unroll 1
        for (int k = 0; k < CD; k += 4) {
            float4 av = *(const float4*)(a + k);
            a0 += av.x * Wcp[(size_t)(k + 0) * 640 + c];
            a1 += av.y * Wcp[(size_t)(k + 1) * 640 + c];
            a2 += av.z * Wcp[(size_t)(k + 2) * 640 + c];
            a3 += av.w * Wcp[(size_t)(k + 3) * 640 + c];
        }
    } else {
        int c2 = c - 640;
        bias = bgp[c2];
        const float* g = gpool + b * HD;
        #pragma unroll 1
        for (int k = 0; k < HD; k += 4) {
            float4 gv = *(const float4*)(g + k);
            a0 += gv.x * Wgp[(size_t)(k + 0) * 640 + c2];
            a1 += gv.y * Wgp[(size_t)(k + 1) * 640 + c2];
            a2 += gv.z * Wgp[(size_t)(k + 2) * 640 + c2];
            a3 += gv.w * Wgp[(size_t)(k + 3) * 640 + c2];
        }
    }
    combined[idx] = bias + (a0 + a1) + (a2 + a3);
}

__global__ void tail2_kernel(const float* __restrict__ combined, const float* __restrict__ Wf1,
                             const float* __restrict__ bf1,
                             const float* __restrict__ g, const float* __restrict__ be,
                             const float* __restrict__ mn, const float* __restrict__ vr,
                             float* __restrict__ h)
{
    int idx = blockIdx.x * 256 + threadIdx.x;
    int b = idx / OD, c = idx % OD;
    const float* a = combined + b * OD;
    float a0 = 0.f, a1 = 0.f, a2 = 0.f, a3 = 0.f;
    #pragma unroll 1
    for (int k = 0; k < OD; k += 4) {
        float4 av = *(const float4*)(a + k);
        a0 += av.x * Wf1[(size_t)(k + 0) * OD + c];
        a1 += av.y * Wf1[(size_t)(k + 1) * OD + c];
        a2 += av.z * Wf1[(size_t)(k + 2) * OD + c];
        a3 += av.w * Wf1[(size_t)(k + 3) * OD + c];
    }
    float acc = bf1[c] + (a0 + a1) + (a2 + a3);
    float x = (acc - mn[c]) * rsqrtf(vr[c] + 1e-5f) * g[c] + be[c];
    h[idx] = fmaxf(x, 0.f);
}

__global__ void tail3_kernel(const float* __restrict__ h, const float* __restrict__ Wf2,
                             const float* __restrict__ bf2, float* __restrict__ out)
{
    int idx = blockIdx.x * 256 + threadIdx.x;
    int b = idx / OD, c = idx % OD;
    const float* a = h + b * OD;
    float a0 = 0.f, a1 = 0.f, a2 = 0.f, a3 = 0.f;
    #pragma unroll 1
    for (int k = 0; k < OD; k += 4) {
        float4 av = *(const float4*)(a + k);
        a0 += av.x * Wf2[(size_t)(k + 0) * OD + c];
        a1 += av.y * Wf2[(size_t)(k + 1) * OD + c];
        a2 += av.z * Wf2[(size_t)(k + 2) * OD + c];
        a3 += av.w * Wf2[(size_t)(k + 3) * OD + c];
    }
    out[idx] = bf2[c] + (a0 + a1) + (a2 + a3);
}

// ---------------- launch ----------------------------------------------------
extern "C" void kernel_launch(void* const* d_in, const int* in_sizes, int n_in,
                              void* d_out, int out_size, void* d_ws, size_t ws_size,
                              hipStream_t stream)
{
    const float* cf  = (const float*)d_in[0];
    const float* gf  = (const float*)d_in[1];
    const float* cw  = (const float*)d_in[2];
    const float* Wq  = (const float*)d_in[3];  const float* bq  = (const float*)d_in[4];
    const float* Wk  = (const float*)d_in[5];  const float* bk  = (const float*)d_in[6];
    const float* Wv  = (const float*)d_in[7];  const float* bv  = (const float*)d_in[8];
    const float* Wcp = (const float*)d_in[9];  const float* bcp = (const float*)d_in[10];
    const float* Wgp = (const float*)d_in[11]; const float* bgp = (const float*)d_in[12];
    const float* Wf1 = (const float*)d_in[13]; const float* bf1 = (const float*)d_in[14];
    const float* bng = (const float*)d_in[15]; const float* bnb = (const float*)d_in[16];
    const float* bnm = (const float*)d_in[17]; const float* bnv = (const float*)d_in[18];
    const float* Wf2 = (const float*)d_in[19]; const float* bf2 = (const float*)d_in[20];

    float* out  = (float*)d_out;         // [32,1280]
    float* attn = out + NB * OD;         // [32,1024,1024] fp32

    char* w = (char*)d_ws;
    ushort_t* Qb  = (ushort_t*)w; w += (size_t)NB * NN * HD * 2;
    ushort_t* Kb  = (ushort_t*)w; w += (size_t)NB * NN * HD * 2;
    ushort_t* Wqt = (ushort_t*)w; w += (size_t)HD * CD * 2;
    ushort_t* Wkt = (ushort_t*)w; w += (size_t)HD * GD * 2;
    float* pooled   = (float*)w; w += (size_t)NB * CD * 4;   // zeroed together:
    float* gpool    = (float*)w; w += (size_t)NB * HD * 4;   //   pooled,gpool,
    float* colsum   = (float*)w; w += (size_t)NB * NN * 4;   //   colsum,gws
    float* gws      = (float*)w; w += (size_t)NB * GD * 4;   //   (contiguous)
    float* combined = (float*)w; w += (size_t)NB * OD * 4;
    float* hbuf     = (float*)w; w += (size_t)NB * OD * 4;

    // zero pooled+gpool+colsum+gws in one pass (contiguous): 32*2560 floats
    const int nz = NB * (CD + HD + NN + GD);
    zero_kernel<<<dim3((nz + 255) / 256), dim3(256), 0, stream>>>(pooled, nz);
    convw_kernel<<<dim3(CD), dim3(256), 0, stream>>>(Wq, Wqt, CD);
    convw_kernel<<<dim3(GD), dim3(256), 0, stream>>>(Wk, Wkt, GD);
    pool_kernel<<<dim3(16, 32), dim3(256), 0, stream>>>(cf, pooled);

    proj_kernel<CD><<<dim3(256, 2), dim3(256), 0, stream>>>(cf, Wqt, bq, Qb);
    proj_kernel<GD><<<dim3(256, 2), dim3(256), 0, stream>>>(gf, Wkt, bk, Kb);

    attn_kernel<<<dim3(32, 64), dim3(256), 0, stream>>>(Qb, Kb, cw, attn, colsum);

    wpool_kernel<<<dim3(8, 32), dim3(192), 0, stream>>>(gf, colsum, gws);
    vproj_kernel<<<dim3(32), dim3(256), 0, stream>>>(gws, Wv, bv, gpool);

    tail1_kernel<<<dim3(160), dim3(256), 0, stream>>>(pooled, gpool, Wcp, bcp, Wgp, bgp, combined);
    tail2_kernel<<<dim3(160), dim3(256), 0, stream>>>(combined, Wf1, bf1, bng, bnb, bnm, bnv, hbuf);
    tail3_kernel<<<dim3(160), dim3(256), 0, stream>>>(hbuf, Wf2, bf2, out);
}

// Round 4
// 799.245 us; speedup vs baseline: 1.2566x; 1.2566x over previous
//
#include <hip/hip_runtime.h>
#include <stdint.h>

typedef short    v8s  __attribute__((ext_vector_type(8)));
typedef float    v4f  __attribute__((ext_vector_type(4)));
typedef unsigned short u16x8 __attribute__((ext_vector_type(8)));
typedef unsigned short ushort_t;

#define NB   32
#define NN   1024
#define CD   896
#define GD   384
#define HD   256
#define OD   1280
#define SP   1028   // LDS score pitch (floats): p/4 odd -> conflict-floor b128 reads

static __device__ __forceinline__ unsigned short f2bf(float f) {
    union { float f; unsigned u; } v; v.f = f;
    unsigned r = v.u + 0x7fffu + ((v.u >> 16) & 1u);
    return (unsigned short)(r >> 16);
}

static __device__ __forceinline__ v4f mfma16(v8s a, v8s b, v4f c) {
    return __builtin_amdgcn_mfma_f32_16x16x32_bf16(a, b, c, 0, 0, 0);
}

// stage 16 fp32 -> 16 bf16 into LDS (two 16B stores)
static __device__ __forceinline__ void stage_cvt16(const float* __restrict__ src, ushort_t* dst) {
    const float4* s4 = (const float4*)src;
    float4 f0 = s4[0], f1 = s4[1], f2 = s4[2], f3 = s4[3];
    u16x8 p0, p1;
    p0[0]=f2bf(f0.x); p0[1]=f2bf(f0.y); p0[2]=f2bf(f0.z); p0[3]=f2bf(f0.w);
    p0[4]=f2bf(f1.x); p0[5]=f2bf(f1.y); p0[6]=f2bf(f1.z); p0[7]=f2bf(f1.w);
    p1[0]=f2bf(f2.x); p1[1]=f2bf(f2.y); p1[2]=f2bf(f2.z); p1[3]=f2bf(f2.w);
    p1[4]=f2bf(f3.x); p1[5]=f2bf(f3.y); p1[6]=f2bf(f3.z); p1[7]=f2bf(f3.w);
    *(u16x8*)dst = p0;
    *(u16x8*)(dst + 8) = p1;
}

static __device__ __forceinline__ void stage_copy16(const ushort_t* __restrict__ src, ushort_t* dst) {
    const u16x8* s = (const u16x8*)src;
    u16x8 a = s[0], b = s[1];
    *(u16x8*)dst = a;
    *(u16x8*)(dst + 8) = b;
}

// ---------------- weight transpose+convert: W[k][n] f32 -> Wt[n][k] bf16 ----
__global__ void convw_kernel(const float* __restrict__ W, ushort_t* __restrict__ Wt, int Kd) {
    int idx = blockIdx.x * 256 + threadIdx.x;      // total = Kd*256
    int k = idx >> 8, n = idx & 255;
    Wt[(size_t)n * Kd + k] = f2bf(W[idx]);
}

__global__ void zero_kernel(float* __restrict__ p, int n) {
    int i = blockIdx.x * 256 + threadIdx.x;
    if (i < n) p[i] = 0.f;
}

// ---------------- cluster pooled mean: 256 blocks, float4, atomic combine ---
__global__ void pool_kernel(const float* __restrict__ cf, float* __restrict__ pooled) {
    int b = blockIdx.y, chunk = blockIdx.x, t = threadIdx.x;
    if (t >= 224) return;                          // 224 float4 = 896 floats
    const float4* p = (const float4*)(cf + (size_t)(b * NN + chunk * 128) * CD) + t;
    float4 s = {0.f, 0.f, 0.f, 0.f};
    #pragma unroll 4
    for (int n = 0; n < 128; ++n) {
        float4 v = p[(size_t)n * 224];
        s.x += v.x; s.y += v.y; s.z += v.z; s.w += v.w;
    }
    const float sc = 1.f / 1024.f;
    float* dst = pooled + b * CD + t * 4;
    atomicAdd(dst + 0, s.x * sc);
    atomicAdd(dst + 1, s.y * sc);
    atomicAdd(dst + 2, s.z * sc);
    atomicAdd(dst + 3, s.w * sc);
}

// ---------------- projection GEMM: C_bf16[M,256] = A_f32[M,KD] @ Wt^T + bias -
template<int KD>
__global__ __launch_bounds__(256) void proj_kernel(
    const float* __restrict__ A, const ushort_t* __restrict__ Wt,
    const float* __restrict__ bias, ushort_t* __restrict__ C)
{
    __shared__ ushort_t lA[128 * 40];
    __shared__ ushort_t lB[128 * 40];
    const int tid  = threadIdx.x;
    const int m0   = blockIdx.x * 128;
    const int n0   = blockIdx.y * 128;
    const int lane = tid & 63, wave = tid >> 6;
    const int l15  = lane & 15, quad = lane >> 4;
    const int wrow = (wave >> 1) * 64, wcol = (wave & 1) * 64;
    const int srow = tid >> 1, shalf = tid & 1;

    v4f acc[4][4];
    #pragma unroll
    for (int i = 0; i < 4; ++i)
        #pragma unroll
        for (int j = 0; j < 4; ++j) acc[i][j] = v4f{0.f, 0.f, 0.f, 0.f};

    for (int kt = 0; kt < KD / 32; ++kt) {
        stage_cvt16(A + (size_t)(m0 + srow) * KD + kt * 32 + shalf * 16,
                    &lA[srow * 40 + shalf * 16]);
        stage_copy16(Wt + (size_t)(n0 + srow) * KD + kt * 32 + shalf * 16,
                     &lB[srow * 40 + shalf * 16]);
        __syncthreads();
        v8s af[4], bfr[4];
        #pragma unroll
        for (int rt = 0; rt < 4; ++rt) af[rt]  = *(const v8s*)&lA[(wrow + rt * 16 + l15) * 40 + quad * 8];
        #pragma unroll
        for (int ct = 0; ct < 4; ++ct) bfr[ct] = *(const v8s*)&lB[(wcol + ct * 16 + l15) * 40 + quad * 8];
        #pragma unroll
        for (int rt = 0; rt < 4; ++rt)
            #pragma unroll
            for (int ct = 0; ct < 4; ++ct)
                acc[rt][ct] = mfma16(af[rt], bfr[ct], acc[rt][ct]);
        __syncthreads();
    }

    #pragma unroll
    for (int ct = 0; ct < 4; ++ct) {
        int col = n0 + wcol + ct * 16 + l15;
        float bv = bias[col];
        #pragma unroll
        for (int rt = 0; rt < 4; ++rt)
            #pragma unroll
            for (int r = 0; r < 4; ++r) {
                int row = m0 + wrow + rt * 16 + quad * 4 + r;
                C[(size_t)row * 256 + col] = f2bf(acc[rt][ct][r] + bv);
            }
    }
}

// ---------------- fused attention: QK^T + log(w) -> softmax -> attn + colsum
// Block: 512 threads (8 waves), owns M=16 rows of one batch, full N=1024.
// LDS: S[16][SP] fp32 = 65.8 KB -> 2 blocks/CU: block A's softmax/store phase
// overlaps block B's MFMA/gather phase on the same CU.
__global__ __launch_bounds__(512, 4) void attn_kernel(
    const ushort_t* __restrict__ Qb, const ushort_t* __restrict__ Kb,
    const float* __restrict__ cw,
    float* __restrict__ attn, float* __restrict__ colsum)
{
    __shared__ float S[16 * SP];
    const int bat = blockIdx.x;          // batch on x -> batch%8 pins to XCD (K L2 reuse)
    const int m0  = blockIdx.y * 16;
    const int tid = threadIdx.x;
    const int lane = tid & 63, wave = tid >> 6;
    const int l15 = lane & 15, quad = lane >> 4;

    // ---- Phase 1: S[m][n] = scale*Q@K^T + log(w+1e-8), wave handles 128 cols
    v8s af[8];
    #pragma unroll
    for (int ks = 0; ks < 8; ++ks)
        af[ks] = *(const v8s*)(Qb + (size_t)(bat * NN + m0 + l15) * HD + ks * 32 + quad * 8);

    const int n0w = wave * 128;
    #pragma unroll 2
    for (int ct = 0; ct < 8; ++ct) {
        const int col = n0w + ct * 16 + l15;
        v8s bfr[8];
        #pragma unroll
        for (int ks = 0; ks < 8; ++ks)
            bfr[ks] = *(const v8s*)(Kb + (size_t)(bat * NN + col) * HD + ks * 32 + quad * 8);
        // prefetch cw for this tile
        float w0[4];
        const size_t cwb = ((size_t)bat << 20) + col;
        #pragma unroll
        for (int r = 0; r < 4; ++r)
            w0[r] = cw[cwb + (size_t)(m0 + quad * 4 + r) * NN];
        v4f acc0 = {0.f, 0.f, 0.f, 0.f};
        #pragma unroll
        for (int ks = 0; ks < 8; ++ks)
            acc0 = mfma16(af[ks], bfr[ks], acc0);
        #pragma unroll
        for (int r = 0; r < 4; ++r) {
            const int row0 = quad * 4 + r;
            S[row0 * SP + col] = acc0[r] * 0.0625f + __logf(w0[r] + 1e-8f);
        }
    }
    __syncthreads();

    // ---- Phase 2: per-row softmax in LDS (2 rows/wave), write attn to global,
    //               accumulate per-column partial sums in registers
    float4 cs[4];
    #pragma unroll
    for (int i = 0; i < 4; ++i) cs[i] = float4{0.f, 0.f, 0.f, 0.f};

    #pragma unroll 1
    for (int rr = 0; rr < 2; ++rr) {
        const int row = wave * 2 + rr;
        float* Srow = &S[row * SP];
        float4 v[4];
        #pragma unroll
        for (int i = 0; i < 4; ++i) v[i] = *(float4*)(Srow + i * 256 + lane * 4);
        float m = -1e30f;
        #pragma unroll
        for (int i = 0; i < 4; ++i)
            m = fmaxf(m, fmaxf(fmaxf(v[i].x, v[i].y), fmaxf(v[i].z, v[i].w)));
        #pragma unroll
        for (int off = 1; off <= 32; off <<= 1) m = fmaxf(m, __shfl_xor(m, off));
        float s = 0.f;
        #pragma unroll
        for (int i = 0; i < 4; ++i) {
            v[i].x = __expf(v[i].x - m); v[i].y = __expf(v[i].y - m);
            v[i].z = __expf(v[i].z - m); v[i].w = __expf(v[i].w - m);
            s += v[i].x + v[i].y + v[i].z + v[i].w;
        }
        #pragma unroll
        for (int off = 1; off <= 32; off <<= 1) s += __shfl_xor(s, off);
        const float inv = 1.0f / s;
        float* grow = attn + ((size_t)bat << 20) + (size_t)(m0 + row) * NN;
        #pragma unroll
        for (int i = 0; i < 4; ++i) {
            v[i].x *= inv; v[i].y *= inv; v[i].z *= inv; v[i].w *= inv;
            *(float4*)(grow + i * 256 + lane * 4) = v[i];
            cs[i].x += v[i].x; cs[i].y += v[i].y; cs[i].z += v[i].z; cs[i].w += v[i].w;
        }
    }

    // ---- Phase 3: cross-wave colsum reduce (reuse S[0..8191] as [8][1024])
    __syncthreads();                     // all waves done reading their S rows
    #pragma unroll
    for (int i = 0; i < 4; ++i)
        *(float4*)&S[wave * 1024 + i * 256 + lane * 4] = cs[i];
    __syncthreads();
    {
        const int c = tid * 2;           // 512 threads x 2 cols = 1024
        float s0 = 0.f, s1 = 0.f;
        #pragma unroll
        for (int w = 0; w < 8; ++w) {
            float2 p = *(const float2*)&S[w * 1024 + c];
            s0 += p.x; s1 += p.y;
        }
        atomicAdd(&colsum[(size_t)bat * NN + c + 0], s0);
        atomicAdd(&colsum[(size_t)bat * NN + c + 1], s1);
    }
}

// ---------------- weighted gf pooling: gws[b,:] = (1/N) colsum[b,:] @ gf[b] -
// grid (8 chunks, 32 b), 192 threads (float2 over GD=384)
__global__ __launch_bounds__(192) void wpool_kernel(
    const float* __restrict__ gf, const float* __restrict__ colsum,
    float* __restrict__ gws)
{
    const int b = blockIdx.y, m0 = blockIdx.x * 128, t = threadIdx.x;
    const float2* base = (const float2*)(gf + (size_t)(b * NN + m0) * GD);
    const float* wbase = colsum + (size_t)b * NN + m0;
    float sx = 0.f, sy = 0.f;
    #pragma unroll 4
    for (int m = 0; m < 128; ++m) {
        const float w = wbase[m] * (1.f / 1024.f);
        float2 v = base[(size_t)m * (GD / 2) + t];
        sx += w * v.x; sy += w * v.y;
    }
    atomicAdd(&gws[b * GD + 2 * t + 0], sx);
    atomicAdd(&gws[b * GD + 2 * t + 1], sy);
}

// ---------------- tiny V projection: gpool[b,d] = gws[b,:] @ Wv[:,d] + bv[d] -
__global__ __launch_bounds__(256) void vproj_kernel(
    const float* __restrict__ gws, const float* __restrict__ Wv,
    const float* __restrict__ bv, float* __restrict__ gpool)
{
    const int b = blockIdx.x, d = threadIdx.x;
    const float* g = gws + (size_t)b * GD;
    float acc = bv[d];
    #pragma unroll 8
    for (int k = 0; k < GD; ++k) acc += g[k] * Wv[(size_t)k * HD + d];
    gpool[b * HD + d] = acc;
}

// ---------------- tails (fp32 vector) ---------------------------------------
__global__ void tail1_kernel(const float* __restrict__ pooled, const float* __restrict__ gpool,
                             const float* __restrict__ Wcp, const float* __restrict__ bcp,
                             const float* __restrict__ Wgp, const float* __restrict__ bgp,
                             float* __restrict__ combined)
{
    int idx = blockIdx.x * 256 + threadIdx.x;  // 32*1280
    int b = idx / OD, c = idx % OD;
    float acc;
    if (c < 640) {
        acc = bcp[c];
        const float* a = pooled + b * CD;
        for (int k = 0; k < CD; ++k) acc += a[k] * Wcp[k * 640 + c];
    } else {
        int c2 = c - 640;
        acc = bgp[c2];
        const float* g = gpool + b * HD;
        for (int k = 0; k < HD; ++k) acc += g[k] * Wgp[k * 640 + c2];
    }
    combined[idx] = acc;
}

__global__ void tail2_kernel(const float* __restrict__ combined, const float* __restrict__ Wf1,
                             const float* __restrict__ bf1,
                             const float* __restrict__ g, const float* __restrict__ be,
                             const float* __restrict__ mn, const float* __restrict__ vr,
                             float* __restrict__ h)
{
    int idx = blockIdx.x * 256 + threadIdx.x;
    int b = idx / OD, c = idx % OD;
    float acc = bf1[c];
    const float* a = combined + b * OD;
    for (int k = 0; k < OD; ++k) acc += a[k] * Wf1[k * OD + c];
    float x = (acc - mn[c]) * rsqrtf(vr[c] + 1e-5f) * g[c] + be[c];
    h[idx] = fmaxf(x, 0.f);
}

__global__ void tail3_kernel(const float* __restrict__ h, const float* __restrict__ Wf2,
                             const float* __restrict__ bf2, float* __restrict__ out)
{
    int idx = blockIdx.x * 256 + threadIdx.x;
    int b = idx / OD, c = idx % OD;
    float acc = bf2[c];
    const float* a = h + b * OD;
    for (int k = 0; k < OD; ++k) acc += a[k] * Wf2[k * OD + c];
    out[idx] = acc;
}

// ---------------- launch ----------------------------------------------------
extern "C" void kernel_launch(void* const* d_in, const int* in_sizes, int n_in,
                              void* d_out, int out_size, void* d_ws, size_t ws_size,
                              hipStream_t stream)
{
    const float* cf  = (const float*)d_in[0];
    const float* gf  = (const float*)d_in[1];
    const float* cw  = (const float*)d_in[2];
    const float* Wq  = (const float*)d_in[3];  const float* bq  = (const float*)d_in[4];
    const float* Wk  = (const float*)d_in[5];  const float* bk  = (const float*)d_in[6];
    const float* Wv  = (const float*)d_in[7];  const float* bv  = (const float*)d_in[8];
    const float* Wcp = (const float*)d_in[9];  const float* bcp = (const float*)d_in[10];
    const float* Wgp = (const float*)d_in[11]; const float* bgp = (const float*)d_in[12];
    const float* Wf1 = (const float*)d_in[13]; const float* bf1 = (const float*)d_in[14];
    const float* bng = (const float*)d_in[15]; const float* bnb = (const float*)d_in[16];
    const float* bnm = (const float*)d_in[17]; const float* bnv = (const float*)d_in[18];
    const float* Wf2 = (const float*)d_in[19]; const float* bf2 = (const float*)d_in[20];

    float* out  = (float*)d_out;         // [32,1280]
    float* attn = out + NB * OD;         // [32,1024,1024] fp32

    char* w = (char*)d_ws;
    ushort_t* Qb  = (ushort_t*)w; w += (size_t)NB * NN * HD * 2;
    ushort_t* Kb  = (ushort_t*)w; w += (size_t)NB * NN * HD * 2;
    ushort_t* Wqt = (ushort_t*)w; w += (size_t)HD * CD * 2;
    ushort_t* Wkt = (ushort_t*)w; w += (size_t)HD * GD * 2;
    float* pooled   = (float*)w; w += (size_t)NB * CD * 4;   // zeroed together:
    float* gpool    = (float*)w; w += (size_t)NB * HD * 4;   //   pooled,gpool,
    float* colsum   = (float*)w; w += (size_t)NB * NN * 4;   //   colsum,gws
    float* gws      = (float*)w; w += (size_t)NB * GD * 4;   //   (contiguous)
    float* combined = (float*)w; w += (size_t)NB * OD * 4;
    float* hbuf     = (float*)w; w += (size_t)NB * OD * 4;

    // zero pooled+gpool+colsum+gws in one pass (contiguous): 32*2560 floats
    const int nz = NB * (CD + HD + NN + GD);
    zero_kernel<<<dim3((nz + 255) / 256), dim3(256), 0, stream>>>(pooled, nz);
    convw_kernel<<<dim3(CD), dim3(256), 0, stream>>>(Wq, Wqt, CD);
    convw_kernel<<<dim3(GD), dim3(256), 0, stream>>>(Wk, Wkt, GD);
    pool_kernel<<<dim3(8, 32), dim3(256), 0, stream>>>(cf, pooled);

    proj_kernel<CD><<<dim3(256, 2), dim3(256), 0, stream>>>(cf, Wqt, bq, Qb);
    proj_kernel<GD><<<dim3(256, 2), dim3(256), 0, stream>>>(gf, Wkt, bk, Kb);

    attn_kernel<<<dim3(32, 64), dim3(512), 0, stream>>>(Qb, Kb, cw, attn, colsum);

    wpool_kernel<<<dim3(8, 32), dim3(192), 0, stream>>>(gf, colsum, gws);
    vproj_kernel<<<dim3(32), dim3(256), 0, stream>>>(gws, Wv, bv, gpool);

    tail1_kernel<<<dim3(160), dim3(256), 0, stream>>>(pooled, gpool, Wcp, bcp, Wgp, bgp, combined);
    tail2_kernel<<<dim3(160), dim3(256), 0, stream>>>(combined, Wf1, bf1, bng, bnb, bnm, bnv, hbuf);
    tail3_kernel<<<dim3(160), dim3(256), 0, stream>>>(hbuf, Wf2, bf2, out);
}

// Round 5
// 690.395 us; speedup vs baseline: 1.4547x; 1.1577x over previous
//
#include <hip/hip_runtime.h>
#include <stdint.h>

typedef short    v8s  __attribute__((ext_vector_type(8)));
typedef float    v4f  __attribute__((ext_vector_type(4)));
typedef unsigned short u16x8 __attribute__((ext_vector_type(8)));
typedef unsigned short ushort_t;

#define NB   32
#define NN   1024
#define CD   896
#define GD   384
#define HD   256
#define OD   1280
#define SP   1028   // LDS score pitch (floats): p/4 odd -> conflict-floor b128 reads

static __device__ __forceinline__ unsigned short f2bf(float f) {
    union { float f; unsigned u; } v; v.f = f;
    unsigned r = v.u + 0x7fffu + ((v.u >> 16) & 1u);
    return (unsigned short)(r >> 16);
}

static __device__ __forceinline__ v4f mfma16(v8s a, v8s b, v4f c) {
    return __builtin_amdgcn_mfma_f32_16x16x32_bf16(a, b, c, 0, 0, 0);
}

// stage 16 fp32 -> 16 bf16 into LDS (two 16B stores)
static __device__ __forceinline__ void stage_cvt16(const float* __restrict__ src, ushort_t* dst) {
    const float4* s4 = (const float4*)src;
    float4 f0 = s4[0], f1 = s4[1], f2 = s4[2], f3 = s4[3];
    u16x8 p0, p1;
    p0[0]=f2bf(f0.x); p0[1]=f2bf(f0.y); p0[2]=f2bf(f0.z); p0[3]=f2bf(f0.w);
    p0[4]=f2bf(f1.x); p0[5]=f2bf(f1.y); p0[6]=f2bf(f1.z); p0[7]=f2bf(f1.w);
    p1[0]=f2bf(f2.x); p1[1]=f2bf(f2.y); p1[2]=f2bf(f2.z); p1[3]=f2bf(f2.w);
    p1[4]=f2bf(f3.x); p1[5]=f2bf(f3.y); p1[6]=f2bf(f3.z); p1[7]=f2bf(f3.w);
    *(u16x8*)dst = p0;
    *(u16x8*)(dst + 8) = p1;
}

static __device__ __forceinline__ void stage_copy16(const ushort_t* __restrict__ src, ushort_t* dst) {
    const u16x8* s = (const u16x8*)src;
    u16x8 a = s[0], b = s[1];
    *(u16x8*)dst = a;
    *(u16x8*)(dst + 8) = b;
}

// ---------------- weight transpose+convert: W[k][n] f32 -> Wt[n][k] bf16 ----
__global__ void convw_kernel(const float* __restrict__ W, ushort_t* __restrict__ Wt, int Kd) {
    int idx = blockIdx.x * 256 + threadIdx.x;      // total = Kd*256
    int k = idx >> 8, n = idx & 255;
    Wt[(size_t)n * Kd + k] = f2bf(W[idx]);
}

__global__ void zero_kernel(float* __restrict__ p, int n) {
    int i = blockIdx.x * 256 + threadIdx.x;
    if (i < n) p[i] = 0.f;
}

// ---------------- cluster pooled mean: 1024 blocks (32 rows each), 4-acc ILP
__global__ void pool_kernel(const float* __restrict__ cf, float* __restrict__ pooled) {
    int b = blockIdx.y, chunk = blockIdx.x, t = threadIdx.x;
    if (t >= 224) return;                          // 224 float4 = 896 floats
    const float4* p = (const float4*)(cf + (size_t)(b * NN + chunk * 32) * CD) + t;
    float4 s0{0,0,0,0}, s1{0,0,0,0}, s2{0,0,0,0}, s3{0,0,0,0};
    #pragma unroll 1
    for (int n = 0; n < 32; n += 4) {
        float4 v0 = p[(size_t)(n + 0) * 224];
        float4 v1 = p[(size_t)(n + 1) * 224];
        float4 v2 = p[(size_t)(n + 2) * 224];
        float4 v3 = p[(size_t)(n + 3) * 224];
        s0.x += v0.x; s0.y += v0.y; s0.z += v0.z; s0.w += v0.w;
        s1.x += v1.x; s1.y += v1.y; s1.z += v1.z; s1.w += v1.w;
        s2.x += v2.x; s2.y += v2.y; s2.z += v2.z; s2.w += v2.w;
        s3.x += v3.x; s3.y += v3.y; s3.z += v3.z; s3.w += v3.w;
    }
    const float sc = 1.f / 1024.f;
    float* dst = pooled + b * CD + t * 4;
    atomicAdd(dst + 0, (s0.x + s1.x + s2.x + s3.x) * sc);
    atomicAdd(dst + 1, (s0.y + s1.y + s2.y + s3.y) * sc);
    atomicAdd(dst + 2, (s0.z + s1.z + s2.z + s3.z) * sc);
    atomicAdd(dst + 3, (s0.w + s1.w + s2.w + s3.w) * sc);
}

// ---------------- projection GEMM: C_bf16[M,256] = A_f32[M,KD] @ Wt^T + bias
// Single N-pass: block = 128 rows x 256 cols, 512 threads (8 waves, 2x4 of
// 64x64). A (cf/gf) is read ONCE (was twice with grid.y=2).
template<int KD>
__global__ __launch_bounds__(512, 4) void proj_kernel(
    const float* __restrict__ A, const ushort_t* __restrict__ Wt,
    const float* __restrict__ bias, ushort_t* __restrict__ C)
{
    __shared__ ushort_t lA[128 * 40];
    __shared__ ushort_t lB[256 * 40];
    const int tid  = threadIdx.x;
    const int m0   = blockIdx.x * 128;
    const int lane = tid & 63, wave = tid >> 6;
    const int l15  = lane & 15, quad = lane >> 4;
    const int wrow = (wave >> 2) * 64, wcol = (wave & 3) * 64;
    const int srow = tid >> 1, shalf = tid & 1;    // B rows 0..255; A rows 0..127 (tid<256)

    v4f acc[4][4];
    #pragma unroll
    for (int i = 0; i < 4; ++i)
        #pragma unroll
        for (int j = 0; j < 4; ++j) acc[i][j] = v4f{0.f, 0.f, 0.f, 0.f};

    for (int kt = 0; kt < KD / 32; ++kt) {
        if (tid < 256)
            stage_cvt16(A + (size_t)(m0 + srow) * KD + kt * 32 + shalf * 16,
                        &lA[srow * 40 + shalf * 16]);
        stage_copy16(Wt + (size_t)srow * KD + kt * 32 + shalf * 16,
                     &lB[srow * 40 + shalf * 16]);
        __syncthreads();
        v8s af[4], bfr[4];
        #pragma unroll
        for (int rt = 0; rt < 4; ++rt) af[rt]  = *(const v8s*)&lA[(wrow + rt * 16 + l15) * 40 + quad * 8];
        #pragma unroll
        for (int ct = 0; ct < 4; ++ct) bfr[ct] = *(const v8s*)&lB[(wcol + ct * 16 + l15) * 40 + quad * 8];
        #pragma unroll
        for (int rt = 0; rt < 4; ++rt)
            #pragma unroll
            for (int ct = 0; ct < 4; ++ct)
                acc[rt][ct] = mfma16(af[rt], bfr[ct], acc[rt][ct]);
        __syncthreads();
    }

    #pragma unroll
    for (int ct = 0; ct < 4; ++ct) {
        int col = wcol + ct * 16 + l15;
        float bv = bias[col];
        #pragma unroll
        for (int rt = 0; rt < 4; ++rt)
            #pragma unroll
            for (int r = 0; r < 4; ++r) {
                int row = m0 + wrow + rt * 16 + quad * 4 + r;
                C[(size_t)row * 256 + col] = f2bf(acc[rt][ct][r] + bv);
            }
    }
}

// ---------------- fused attention: QK^T + log(w) -> softmax -> attn + colsum
// Block: 512 threads (8 waves), owns M=32 rows of one batch, full N=1024.
// LDS: S[32][SP] fp32 = 131.6 KB -> 1 block/CU. (Proven R1 config; both the
// 16-row 2-block/CU and register-resident variants measured SLOWER.)
__global__ __launch_bounds__(512) void attn_kernel(
    const ushort_t* __restrict__ Qb, const ushort_t* __restrict__ Kb,
    const float* __restrict__ cw,
    float* __restrict__ attn, float* __restrict__ colsum)
{
    __shared__ float S[32 * SP];
    const int bat = blockIdx.x;          // batch on x -> batch%8 pins to XCD (K L2 reuse)
    const int m0  = blockIdx.y * 32;
    const int tid = threadIdx.x;
    const int lane = tid & 63, wave = tid >> 6;
    const int l15 = lane & 15, quad = lane >> 4;

    // ---- Phase 1: S[m][n] = scale*Q@K^T + log(w+1e-8), wave handles 128 cols
    v8s af[2][8];
    #pragma unroll
    for (int rt = 0; rt < 2; ++rt)
        #pragma unroll
        for (int ks = 0; ks < 8; ++ks)
            af[rt][ks] = *(const v8s*)(Qb + (size_t)(bat * NN + m0 + rt * 16 + l15) * HD + ks * 32 + quad * 8);

    const int n0w = wave * 128;
    #pragma unroll 2
    for (int ct = 0; ct < 8; ++ct) {
        const int col = n0w + ct * 16 + l15;
        v8s bfr[8];
        #pragma unroll
        for (int ks = 0; ks < 8; ++ks)
            bfr[ks] = *(const v8s*)(Kb + (size_t)(bat * NN + col) * HD + ks * 32 + quad * 8);
        // prefetch cw for this tile
        float w0[4], w1[4];
        const size_t cwb = ((size_t)bat << 20) + col;
        #pragma unroll
        for (int r = 0; r < 4; ++r) {
            w0[r] = cw[cwb + (size_t)(m0 + quad * 4 + r) * NN];
            w1[r] = cw[cwb + (size_t)(m0 + 16 + quad * 4 + r) * NN];
        }
        v4f acc0 = {0.f, 0.f, 0.f, 0.f}, acc1 = {0.f, 0.f, 0.f, 0.f};
        #pragma unroll
        for (int ks = 0; ks < 8; ++ks) {
            acc0 = mfma16(af[0][ks], bfr[ks], acc0);
            acc1 = mfma16(af[1][ks], bfr[ks], acc1);
        }
        #pragma unroll
        for (int r = 0; r < 4; ++r) {
            const int row0 = quad * 4 + r;
            S[row0 * SP + col]        = acc0[r] * 0.0625f + __logf(w0[r] + 1e-8f);
            S[(16 + row0) * SP + col] = acc1[r] * 0.0625f + __logf(w1[r] + 1e-8f);
        }
    }
    __syncthreads();

    // ---- Phase 2: per-row softmax in LDS, write attn to global,
    //               accumulate per-column partial sums in registers
    float4 cs[4];
    #pragma unroll
    for (int i = 0; i < 4; ++i) cs[i] = float4{0.f, 0.f, 0.f, 0.f};

    #pragma unroll 1
    for (int rr = 0; rr < 4; ++rr) {
        const int row = wave * 4 + rr;
        float* Srow = &S[row * SP];
        float4 v[4];
        #pragma unroll
        for (int i = 0; i < 4; ++i) v[i] = *(float4*)(Srow + i * 256 + lane * 4);
        float m = -1e30f;
        #pragma unroll
        for (int i = 0; i < 4; ++i)
            m = fmaxf(m, fmaxf(fmaxf(v[i].x, v[i].y), fmaxf(v[i].z, v[i].w)));
        #pragma unroll
        for (int off = 1; off <= 32; off <<= 1) m = fmaxf(m, __shfl_xor(m, off));
        float s = 0.f;
        #pragma unroll
        for (int i = 0; i < 4; ++i) {
            v[i].x = __expf(v[i].x - m); v[i].y = __expf(v[i].y - m);
            v[i].z = __expf(v[i].z - m); v[i].w = __expf(v[i].w - m);
            s += v[i].x + v[i].y + v[i].z + v[i].w;
        }
        #pragma unroll
        for (int off = 1; off <= 32; off <<= 1) s += __shfl_xor(s, off);
        const float inv = 1.0f / s;
        float* grow = attn + ((size_t)bat << 20) + (size_t)(m0 + row) * NN;
        #pragma unroll
        for (int i = 0; i < 4; ++i) {
            v[i].x *= inv; v[i].y *= inv; v[i].z *= inv; v[i].w *= inv;
            *(float4*)(grow + i * 256 + lane * 4) = v[i];
            cs[i].x += v[i].x; cs[i].y += v[i].y; cs[i].z += v[i].z; cs[i].w += v[i].w;
        }
    }

    // ---- Phase 3: cross-wave colsum reduce (reuse S[0..8191] as [8][1024])
    __syncthreads();                     // all waves done reading their S rows
    #pragma unroll
    for (int i = 0; i < 4; ++i)
        *(float4*)&S[wave * 1024 + i * 256 + lane * 4] = cs[i];
    __syncthreads();
    {
        const int c = tid * 2;           // 512 threads x 2 cols = 1024
        float s0 = 0.f, s1 = 0.f;
        #pragma unroll
        for (int w = 0; w < 8; ++w) {
            float2 p = *(const float2*)&S[w * 1024 + c];
            s0 += p.x; s1 += p.y;
        }
        atomicAdd(&colsum[(size_t)bat * NN + c + 0], s0);
        atomicAdd(&colsum[(size_t)bat * NN + c + 1], s1);
    }
}

// ---------------- weighted gf pooling: gws[b,:] = (1/N) colsum[b,:] @ gf[b] -
// grid (8 chunks, 32 b), 192 threads (float2 over GD=384)
__global__ __launch_bounds__(192) void wpool_kernel(
    const float* __restrict__ gf, const float* __restrict__ colsum,
    float* __restrict__ gws)
{
    const int b = blockIdx.y, m0 = blockIdx.x * 128, t = threadIdx.x;
    const float2* base = (const float2*)(gf + (size_t)(b * NN + m0) * GD);
    const float* wbase = colsum + (size_t)b * NN + m0;
    float sx = 0.f, sy = 0.f;
    #pragma unroll 4
    for (int m = 0; m < 128; ++m) {
        const float w = wbase[m] * (1.f / 1024.f);
        float2 v = base[(size_t)m * (GD / 2) + t];
        sx += w * v.x; sy += w * v.y;
    }
    atomicAdd(&gws[b * GD + 2 * t + 0], sx);
    atomicAdd(&gws[b * GD + 2 * t + 1], sy);
}

// ---------------- tiny V projection: gpool[b,d] = gws[b,:] @ Wv[:,d] + bv[d] -
__global__ __launch_bounds__(256) void vproj_kernel(
    const float* __restrict__ gws, const float* __restrict__ Wv,
    const float* __restrict__ bv, float* __restrict__ gpool)
{
    const int b = blockIdx.x, d = threadIdx.x;
    const float* g = gws + (size_t)b * GD;
    float acc = bv[d];
    #pragma unroll 8
    for (int k = 0; k < GD; ++k) acc += g[k] * Wv[(size_t)k * HD + d];
    gpool[b * HD + d] = acc;
}

// ---------------- tails: k-split x4/x5, fp32 atomicAdd, bias on chunk 0 -----
// Each block = one (b, 256-col chunk); blockIdx.y = k-chunk. Raises wave
// parallelism 4-5x on the serial 1280-deep GEMV chains (was 160 blocks =
// 96 idle CUs, 1 wave/SIMD).
__global__ void tail1_kernel(const float* __restrict__ pooled, const float* __restrict__ gpool,
                             const float* __restrict__ Wcp, const float* __restrict__ bcp,
                             const float* __restrict__ Wgp, const float* __restrict__ bgp,
                             float* __restrict__ combined)
{
    int idx = blockIdx.x * 256 + threadIdx.x;  // 32*1280
    int b = idx / OD, c = idx % OD;
    int kc = blockIdx.y;                       // 0..3
    float acc = 0.f;
    if (c < 640) {
        if (kc == 0) acc = bcp[c];
        const float* a = pooled + b * CD;
        const int k0 = kc * 224;
        for (int k = k0; k < k0 + 224; ++k) acc += a[k] * Wcp[k * 640 + c];
    } else {
        int c2 = c - 640;
        if (kc == 0) acc = bgp[c2];
        const float* g = gpool + b * HD;
        const int k0 = kc * 64;
        for (int k = k0; k < k0 + 64; ++k) acc += g[k] * Wgp[k * 640 + c2];
    }
    atomicAdd(&combined[idx], acc);
}

__global__ void tail2_kernel(const float* __restrict__ combined, const float* __restrict__ Wf1,
                             const float* __restrict__ bf1, float* __restrict__ h)
{
    int idx = blockIdx.x * 256 + threadIdx.x;
    int b = idx / OD, c = idx % OD;
    int k0 = blockIdx.y * 256;                 // 5 chunks
    float acc = (blockIdx.y == 0) ? bf1[c] : 0.f;
    const float* a = combined + b * OD;
    for (int k = k0; k < k0 + 256; ++k) acc += a[k] * Wf1[k * OD + c];
    atomicAdd(&h[idx], acc);
}

__global__ void bnrelu_kernel(float* __restrict__ h,
                              const float* __restrict__ g, const float* __restrict__ be,
                              const float* __restrict__ mn, const float* __restrict__ vr)
{
    int idx = blockIdx.x * 256 + threadIdx.x;
    int c = idx % OD;
    float x = (h[idx] - mn[c]) * rsqrtf(vr[c] + 1e-5f) * g[c] + be[c];
    h[idx] = fmaxf(x, 0.f);
}

__global__ void tail3_kernel(const float* __restrict__ h, const float* __restrict__ Wf2,
                             const float* __restrict__ bf2, float* __restrict__ out)
{
    int idx = blockIdx.x * 256 + threadIdx.x;
    int b = idx / OD, c = idx % OD;
    int k0 = blockIdx.y * 256;                 // 5 chunks
    float acc = (blockIdx.y == 0) ? bf2[c] : 0.f;
    const float* a = h + b * OD;
    for (int k = k0; k < k0 + 256; ++k) acc += a[k] * Wf2[k * OD + c];
    atomicAdd(&out[idx], acc);
}

// ---------------- launch ----------------------------------------------------
extern "C" void kernel_launch(void* const* d_in, const int* in_sizes, int n_in,
                              void* d_out, int out_size, void* d_ws, size_t ws_size,
                              hipStream_t stream)
{
    const float* cf  = (const float*)d_in[0];
    const float* gf  = (const float*)d_in[1];
    const float* cw  = (const float*)d_in[2];
    const float* Wq  = (const float*)d_in[3];  const float* bq  = (const float*)d_in[4];
    const float* Wk  = (const float*)d_in[5];  const float* bk  = (const float*)d_in[6];
    const float* Wv  = (const float*)d_in[7];  const float* bv  = (const float*)d_in[8];
    const float* Wcp = (const float*)d_in[9];  const float* bcp = (const float*)d_in[10];
    const float* Wgp = (const float*)d_in[11]; const float* bgp = (const float*)d_in[12];
    const float* Wf1 = (const float*)d_in[13]; const float* bf1 = (const float*)d_in[14];
    const float* bng = (const float*)d_in[15]; const float* bnb = (const float*)d_in[16];
    const float* bnm = (const float*)d_in[17]; const float* bnv = (const float*)d_in[18];
    const float* Wf2 = (const float*)d_in[19]; const float* bf2 = (const float*)d_in[20];

    float* out  = (float*)d_out;         // [32,1280]
    float* attn = out + NB * OD;         // [32,1024,1024] fp32

    char* w = (char*)d_ws;
    ushort_t* Qb  = (ushort_t*)w; w += (size_t)NB * NN * HD * 2;
    ushort_t* Kb  = (ushort_t*)w; w += (size_t)NB * NN * HD * 2;
    ushort_t* Wqt = (ushort_t*)w; w += (size_t)HD * CD * 2;
    ushort_t* Wkt = (ushort_t*)w; w += (size_t)HD * GD * 2;
    float* pooled   = (float*)w; w += (size_t)NB * CD * 4;   // zeroed together:
    float* gpool    = (float*)w; w += (size_t)NB * HD * 4;   //   pooled,gpool,
    float* colsum   = (float*)w; w += (size_t)NB * NN * 4;   //   colsum,gws,
    float* gws      = (float*)w; w += (size_t)NB * GD * 4;   //   combined,hbuf
    float* combined = (float*)w; w += (size_t)NB * OD * 4;   //   (contiguous)
    float* hbuf     = (float*)w; w += (size_t)NB * OD * 4;

    // zero pooled+gpool+colsum+gws+combined+hbuf in one pass (contiguous)
    const int nz = NB * (CD + HD + NN + GD + OD + OD);
    zero_kernel<<<dim3((nz + 255) / 256), dim3(256), 0, stream>>>(pooled, nz);
    zero_kernel<<<dim3((NB * OD + 255) / 256), dim3(256), 0, stream>>>(out, NB * OD);
    convw_kernel<<<dim3(CD), dim3(256), 0, stream>>>(Wq, Wqt, CD);
    convw_kernel<<<dim3(GD), dim3(256), 0, stream>>>(Wk, Wkt, GD);
    pool_kernel<<<dim3(32, 32), dim3(256), 0, stream>>>(cf, pooled);

    proj_kernel<CD><<<dim3(256), dim3(512), 0, stream>>>(cf, Wqt, bq, Qb);
    proj_kernel<GD><<<dim3(256), dim3(512), 0, stream>>>(gf, Wkt, bk, Kb);

    attn_kernel<<<dim3(32, 32), dim3(512), 0, stream>>>(Qb, Kb, cw, attn, colsum);

    wpool_kernel<<<dim3(8, 32), dim3(192), 0, stream>>>(gf, colsum, gws);
    vproj_kernel<<<dim3(32), dim3(256), 0, stream>>>(gws, Wv, bv, gpool);

    tail1_kernel<<<dim3(160, 4), dim3(256), 0, stream>>>(pooled, gpool, Wcp, bcp, Wgp, bgp, combined);
    tail2_kernel<<<dim3(160, 5), dim3(256), 0, stream>>>(combined, Wf1, bf1, hbuf);
    bnrelu_kernel<<<dim3(160), dim3(256), 0, stream>>>(hbuf, bng, bnb, bnm, bnv);
    tail3_kernel<<<dim3(160, 5), dim3(256), 0, stream>>>(hbuf, Wf2, bf2, out);
}